// Round 10
// baseline (224.959 us; speedup 1.0000x reference)
//
#include <hip/hip_runtime.h>

// LIF scan, T=8, N=4M fp32. 256 MiB logical; this device sustains 6.3-6.7 TB/s
// on 1-2-stream patterns (copy/fill) in the same trace.
// Ladder: R1-R4 2.2 TB/s cache-allocate cap -> NT LOADS fixed (R5, ~78 us).
// Burst depth / pipeline / store policy all neutral (R6/R8). R9 footprint
// shrink (256->32 stream-pages/CU) -> 230->225 us total: footprint is a real
// lever. R10 pushes it to the floor: 1 block/CU (grid=256, BLOCK=512, still
// 8 waves/CU) -> exactly 16 stream-pages/CU; XCD-contiguous blockIdx swizzle
// so each XCD owns a contiguous 1/8 of the columns; depth-2 prefetch kept.

#define LIF_THRESH 0.5f
#define LIF_BETA   0.25f
#define LIF_T      8
#define BLOCK      512
#define JITER      8
#define NXCD       8

typedef float v4f __attribute__((ext_vector_type(4)));

__global__ __launch_bounds__(BLOCK) void lif_kernel(const v4f* __restrict__ x,
                                                    v4f* __restrict__ out,
                                                    int n4, int nblk) {
    // Dispatch round-robins blockIdx across XCDs: xcd = blockIdx % 8.
    // Remap so XCD k owns the contiguous block range [k*nblk/8, (k+1)*nblk/8):
    // per-XCD L2/UTCL2 walks one contiguous span per plane instead of a comb.
    const int xcd  = blockIdx.x % NXCD;
    const int slot = blockIdx.x / NXCD;
    const int vblk = xcd * (nblk / NXCD) + slot;

    const int base = vblk * (BLOCK * JITER) + threadIdx.x;

    v4f cur[LIF_T], nxt[LIF_T];

    // Prologue: chunk 0 (nt loads: the R5 win).
#pragma unroll
    for (int t = 0; t < LIF_T; ++t)
        cur[t] = __builtin_nontemporal_load(&x[(size_t)t * n4 + base]);

#pragma unroll
    for (int j = 0; j < JITER; ++j) {
        const int c = base + j * BLOCK;

        // Prefetch chunk j+1 before consuming chunk j (keeps >=8 loads in
        // flight per wave across the compute+store phase).
        if (j + 1 < JITER) {
            const int cn = c + BLOCK;
#pragma unroll
            for (int t = 0; t < LIF_T; ++t)
                nxt[t] = __builtin_nontemporal_load(&x[(size_t)t * n4 + cn]);
        }

        float m0 = 0.f, m1 = 0.f, m2 = 0.f, m3 = 0.f;
#pragma unroll
        for (int t = 0; t < LIF_T; ++t) {
            v4f xt = cur[t];
            m0 = m0 * LIF_BETA + xt.x;
            m1 = m1 * LIF_BETA + xt.y;
            m2 = m2 * LIF_BETA + xt.z;
            m3 = m3 * LIF_BETA + xt.w;

            v4f s;
            s.x = (m0 >= LIF_THRESH) ? 1.f : 0.f;
            s.y = (m1 >= LIF_THRESH) ? 1.f : 0.f;
            s.z = (m2 >= LIF_THRESH) ? 1.f : 0.f;
            s.w = (m3 >= LIF_THRESH) ? 1.f : 0.f;

            m0 = (m0 >= LIF_THRESH) ? 0.f : m0;
            m1 = (m1 >= LIF_THRESH) ? 0.f : m1;
            m2 = (m2 >= LIF_THRESH) ? 0.f : m2;
            m3 = (m3 >= LIF_THRESH) ? 0.f : m3;

            __builtin_nontemporal_store(s, &out[(size_t)t * n4 + c]);
        }

        if (j + 1 < JITER) {
#pragma unroll
            for (int t = 0; t < LIF_T; ++t) cur[t] = nxt[t];
        }
    }
}

extern "C" void kernel_launch(void* const* d_in, const int* in_sizes, int n_in,
                              void* d_out, int out_size, void* d_ws, size_t ws_size,
                              hipStream_t stream) {
    const v4f* x = (const v4f*)d_in[0];
    v4f* out = (v4f*)d_out;

    long long total = in_sizes[0];
    int n = (int)(total / LIF_T);   // 4,194,304 floats per timestep
    int n4 = n / 4;                 // 1,048,576 float4 columns per timestep

    int nblk = n4 / (BLOCK * JITER);   // 256 blocks -> 1 per CU, 8 waves/CU
    dim3 block(BLOCK);
    dim3 grid(nblk);
    lif_kernel<<<grid, block, 0, stream>>>(x, out, n4, nblk);
}